// Round 1
// baseline (4445.039 us; speedup 1.0000x reference)
//
#include <hip/hip_runtime.h>
#include <cmath>

// CRSDCell fp32 baseline pipeline:
//  K1 k_rseq  : r_seq = LN((1-a)*tanh(x @ Wx^T + b))          -> d_out[r region]
//  K2 k_kq    : k = [r_seq,x] @ key_w^T + b ; per-block sums of l2norm(k) -> hs region (scratch)
//  K2b k_qred : q = mean over T                                -> ws
//  Kc k_cvec  : cvec = fftn_b @ fftp_w^T (affine-bias fold)    -> ws
//  K3 k_mem   : top-k episodic + hebbian + rm -> h_mem (B,512) -> ws
//  K4 k_htilde: h~ = gelu(r@B^T + x@U^T + Ub)                  -> hs region (scratch)
//  K5 k_final : LN(h~) -> fftp GEMM -> hs final (in place)
// Note: irfft(rfft(h_norm)*s) == s*h_norm exactly, so the FFT folds into s^2 * GEMM.
// h_prev = r_prev = 0 => Wh_w / A_scale terms are exactly zero. v (val_w) is dead code.

namespace {

__device__ __forceinline__ void gemm_chunk_512(
    float (&sW)[512][20], float (&sA)[32][16],
    const float* __restrict__ W, int wstride,
    const float* __restrict__ A, int astride,
    int m0, int k0, int t, int ty, int tx,
    float (&acc)[4][16])
{
#pragma unroll
  for (int i = 0; i < 8; ++i) {               // stage 512x16 W chunk (2048 float4)
    int idx = t + i * 256;
    int n = idx >> 2, q4 = idx & 3;
    float4 v = *reinterpret_cast<const float4*>(W + (size_t)n * wstride + k0 + q4 * 4);
    *reinterpret_cast<float4*>(&sW[n][q4 * 4]) = v;
  }
  if (t < 128) {                              // stage 32x16 A chunk
    int m = t >> 2, q4 = t & 3;
    float4 v = *reinterpret_cast<const float4*>(A + (size_t)(m0 + m) * astride + k0 + q4 * 4);
    *reinterpret_cast<float4*>(&sA[m][q4 * 4]) = v;
  }
  __syncthreads();
#pragma unroll
  for (int kk = 0; kk < 16; kk += 4) {
    float4 a[4];
#pragma unroll
    for (int i = 0; i < 4; ++i)
      a[i] = *reinterpret_cast<const float4*>(&sA[ty * 4 + i][kk]);
#pragma unroll
    for (int j = 0; j < 16; ++j) {
      float4 w = *reinterpret_cast<const float4*>(&sW[tx + 32 * j][kk]);
#pragma unroll
      for (int i = 0; i < 4; ++i) {
        acc[i][j] = fmaf(a[i].x, w.x, acc[i][j]);
        acc[i][j] = fmaf(a[i].y, w.y, acc[i][j]);
        acc[i][j] = fmaf(a[i].z, w.z, acc[i][j]);
        acc[i][j] = fmaf(a[i].w, w.w, acc[i][j]);
      }
    }
  }
  __syncthreads();
}

} // namespace

// ---------------- K1: r_seq ----------------
__global__ __launch_bounds__(256) void k_rseq(
    const float* __restrict__ x, const float* __restrict__ Wxw,
    const float* __restrict__ Wxb, const float* __restrict__ resa,
    const float* __restrict__ rng, const float* __restrict__ rnb,
    float* __restrict__ rout)
{
  __shared__ float sW[512][20];
  __shared__ float sA[32][16];
  const int t = threadIdx.x, ty = t >> 5, tx = t & 31;
  const int m0 = blockIdx.x * 32;
  float acc[4][16];
#pragma unroll
  for (int i = 0; i < 4; ++i)
#pragma unroll
    for (int j = 0; j < 16; ++j) acc[i][j] = 0.f;

  for (int k0 = 0; k0 < 256; k0 += 16)
    gemm_chunk_512(sW, sA, Wxw, 256, x, 256, m0, k0, t, ty, tx, acc);

  // epilogue: bias, tanh, (1-alpha), LN
  float suml[4] = {0, 0, 0, 0}, sumq[4] = {0, 0, 0, 0};
#pragma unroll
  for (int j = 0; j < 16; ++j) {
    int c = tx + 32 * j;
    float al = 1.f / (1.f + expf(-resa[c >> 7]));
    float bb = Wxb[c];
#pragma unroll
    for (int i = 0; i < 4; ++i) {
      float z = (1.f - al) * tanhf(acc[i][j] + bb);
      acc[i][j] = z;
      suml[i] += z;
      sumq[i] += z * z;
    }
  }
#pragma unroll
  for (int m = 16; m >= 1; m >>= 1) {
#pragma unroll
    for (int i = 0; i < 4; ++i) {
      suml[i] += __shfl_xor(suml[i], m, 64);
      sumq[i] += __shfl_xor(sumq[i], m, 64);
    }
  }
  float mean[4], rstd[4];
#pragma unroll
  for (int i = 0; i < 4; ++i) {
    mean[i] = suml[i] * (1.f / 512.f);
    float var = sumq[i] * (1.f / 512.f) - mean[i] * mean[i];
    rstd[i] = rsqrtf(var + 1e-5f);
  }
#pragma unroll
  for (int j = 0; j < 16; ++j) {
    int c = tx + 32 * j;
    float g = rng[c], bb = rnb[c];
#pragma unroll
    for (int i = 0; i < 4; ++i)
      rout[(size_t)(m0 + ty * 4 + i) * 512 + c] = (acc[i][j] - mean[i]) * rstd[i] * g + bb;
  }
}

// ---------------- K2: k + per-block q partials ----------------
__global__ __launch_bounds__(256) void k_kq(
    const float* __restrict__ rseq, const float* __restrict__ x,
    const float* __restrict__ keyw, const float* __restrict__ keyb,
    float* __restrict__ partial)
{
  __shared__ float sW[128][20];
  __shared__ float sA[32][16];
  __shared__ float qpart[8][128];
  const int t = threadIdx.x, ty = t >> 5, tx = t & 31;
  const int m0 = blockIdx.x * 32;
  float acc[4][4];
#pragma unroll
  for (int i = 0; i < 4; ++i)
#pragma unroll
    for (int j = 0; j < 4; ++j) acc[i][j] = 0.f;

  for (int k0 = 0; k0 < 768; k0 += 16) {
#pragma unroll
    for (int i = 0; i < 2; ++i) {             // 128x16 W chunk = 512 float4
      int idx = t + i * 256;
      int n = idx >> 2, q4 = idx & 3;
      float4 v = *reinterpret_cast<const float4*>(keyw + (size_t)n * 768 + k0 + q4 * 4);
      *reinterpret_cast<float4*>(&sW[n][q4 * 4]) = v;
    }
    if (t < 128) {
      int m = t >> 2, q4 = t & 3;
      const float* Ap = (k0 < 512) ? rseq : x;
      int astr = (k0 < 512) ? 512 : 256;
      int kb = (k0 < 512) ? k0 : (k0 - 512);
      float4 v = *reinterpret_cast<const float4*>(Ap + (size_t)(m0 + m) * astr + kb + q4 * 4);
      *reinterpret_cast<float4*>(&sA[m][q4 * 4]) = v;
    }
    __syncthreads();
#pragma unroll
    for (int kk = 0; kk < 16; kk += 4) {
      float4 a[4];
#pragma unroll
      for (int i = 0; i < 4; ++i)
        a[i] = *reinterpret_cast<const float4*>(&sA[ty * 4 + i][kk]);
#pragma unroll
      for (int j = 0; j < 4; ++j) {
        float4 w = *reinterpret_cast<const float4*>(&sW[tx + 32 * j][kk]);
#pragma unroll
        for (int i = 0; i < 4; ++i) {
          acc[i][j] = fmaf(a[i].x, w.x, acc[i][j]);
          acc[i][j] = fmaf(a[i].y, w.y, acc[i][j]);
          acc[i][j] = fmaf(a[i].z, w.z, acc[i][j]);
          acc[i][j] = fmaf(a[i].w, w.w, acc[i][j]);
        }
      }
    }
    __syncthreads();
  }
  // epilogue: +bias, per-row l2norm, sum rows into block partial
  float kv[4][4], ss[4] = {0, 0, 0, 0};
#pragma unroll
  for (int j = 0; j < 4; ++j) {
    int c = tx + 32 * j;
    float bb = keyb[c];
#pragma unroll
    for (int i = 0; i < 4; ++i) {
      float z = acc[i][j] + bb;
      kv[i][j] = z;
      ss[i] += z * z;
    }
  }
#pragma unroll
  for (int m = 16; m >= 1; m >>= 1)
#pragma unroll
    for (int i = 0; i < 4; ++i) ss[i] += __shfl_xor(ss[i], m, 64);
  float sc[4];
#pragma unroll
  for (int i = 0; i < 4; ++i) sc[i] = 1.f / fmaxf(sqrtf(ss[i]), 1e-8f);
#pragma unroll
  for (int j = 0; j < 4; ++j) {
    float p = 0.f;
#pragma unroll
    for (int i = 0; i < 4; ++i) p += kv[i][j] * sc[i];
    qpart[ty][tx + 32 * j] = p;
  }
  __syncthreads();
  if (t < 128) {
    float tot = 0.f;
#pragma unroll
    for (int g = 0; g < 8; ++g) tot += qpart[g][t];
    partial[(size_t)blockIdx.x * 128 + t] = tot;
  }
}

// ---------------- K2b: reduce partials -> q ----------------
__global__ __launch_bounds__(256) void k_qred(const float* __restrict__ partial,
                                              float* __restrict__ q_ws)
{
  int gid = blockIdx.x * 256 + threadIdx.x;   // 0..1023
  int b = gid >> 7, dk = gid & 127;
  float s = 0.f;
  for (int p = 0; p < 256; ++p) s += partial[(size_t)(b * 256 + p) * 128 + dk];
  q_ws[gid] = s * (1.f / 8192.f);
}

// ---------------- Kc: cvec = fftn_b @ fftp_w^T ----------------
__global__ __launch_bounds__(256) void k_cvec(const float* __restrict__ fb,
                                              const float* __restrict__ fftpw,
                                              float* __restrict__ cvec)
{
  int o = blockIdx.x * 256 + threadIdx.x;     // 0..511
  const float* w = fftpw + (size_t)o * 512;
  float s = 0.f;
  for (int k = 0; k < 512; ++k) s += fb[k] * w[k];
  cvec[o] = s;
}

// ---------------- K3: episodic + hebbian memory -> h_mem ----------------
__global__ __launch_bounds__(256) void k_mem(
    const float* __restrict__ q_ws, const float* __restrict__ mkeys,
    const float* __restrict__ mvals, const float* __restrict__ hebH,
    const float* __restrict__ rmw, const float* __restrict__ rmb,
    const float* __restrict__ mixl, float* __restrict__ hm)
{
  const int b = blockIdx.x, t = threadIdx.x;
  __shared__ float qv[128];
  __shared__ float ssim[256];
  __shared__ float red[256];
  __shared__ float tval[8];
  __shared__ int tidx[8];
  __shared__ float wsm[8];
  __shared__ float vcs[128];

  if (t < 128) qv[t] = q_ws[b * 128 + t];
  __syncthreads();
  red[t] = (t < 128) ? qv[t] * qv[t] : 0.f;
  __syncthreads();
  for (int s = 128; s > 0; s >>= 1) {
    if (t < s) red[t] += red[t + s];
    __syncthreads();
  }
  float qsc = 1.f / fmaxf(sqrtf(red[0]), 1e-8f);

  {   // cosine sim per slot
    const float* mk = mkeys + ((size_t)b * 256 + t) * 128;
    float dot = 0.f, ms = 0.f;
    for (int k = 0; k < 128; ++k) {
      float mv = mk[k];
      dot += qv[k] * mv;
      ms += mv * mv;
    }
    ssim[t] = dot * qsc / fmaxf(sqrtf(ms), 1e-8f);
  }
  __syncthreads();

  // top-8 (desc, lower index wins ties — matches lax.top_k)
  for (int it = 0; it < 8; ++it) {
    if (t < 64) {
      float bv = -1e30f; int bi = 0;
#pragma unroll
      for (int u = 0; u < 4; ++u) {
        int m = t * 4 + u;
        float v = ssim[m];
        if (v > bv) { bv = v; bi = m; }
      }
      for (int off = 32; off; off >>= 1) {
        float ov = __shfl_xor(bv, off, 64);
        int oi = __shfl_xor(bi, off, 64);
        if (ov > bv || (ov == bv && oi < bi)) { bv = ov; bi = oi; }
      }
      if (t == 0) { tval[it] = bv; tidx[it] = bi; ssim[bi] = -1e30f; }
    }
    __syncthreads();
  }
  if (t == 0) {
    float m0 = tval[0], sum = 0.f, e[8];
#pragma unroll
    for (int i = 0; i < 8; ++i) { e[i] = expf(tval[i] - m0); sum += e[i]; }
#pragma unroll
    for (int i = 0; i < 8; ++i) wsm[i] = e[i] / sum;
  }
  __syncthreads();

  float mix = 1.f / (1.f + expf(-mixl[0]));
  if (t < 128) {
    float vh = 0.f;
#pragma unroll
    for (int i = 0; i < 8; ++i)
      vh += wsm[i] * mvals[((size_t)b * 256 + tidx[i]) * 128 + t];
    float vhb = 0.f;
    const float* H = hebH + (size_t)b * 128 * 128;
    for (int k = 0; k < 128; ++k) vhb += qv[k] * H[k * 128 + t];
    vcs[t] = mix * vh + (1.f - mix) * vhb;
  }
  __syncthreads();
  for (int h = t; h < 512; h += 256) {
    float sum = rmb[h];
    const float* wr = rmw + (size_t)h * 128;
    for (int v = 0; v < 128; ++v) sum += vcs[v] * wr[v];
    hm[b * 512 + h] = sum;
  }
}

// ---------------- K4: h_tilde = gelu(r@B^T + x@U^T + Ub) ----------------
__global__ __launch_bounds__(256) void k_htilde(
    const float* __restrict__ rseq, const float* __restrict__ x,
    const float* __restrict__ Bw, const float* __restrict__ Uw,
    const float* __restrict__ Ub, float* __restrict__ ht)
{
  __shared__ float sW[512][20];
  __shared__ float sA[32][16];
  const int t = threadIdx.x, ty = t >> 5, tx = t & 31;
  const int m0 = blockIdx.x * 32;
  float acc[4][16];
#pragma unroll
  for (int i = 0; i < 4; ++i)
#pragma unroll
    for (int j = 0; j < 16; ++j) acc[i][j] = 0.f;

  for (int k0 = 0; k0 < 768; k0 += 16) {
    const float* Wp = (k0 < 512) ? Bw : Uw;
    int wstr = (k0 < 512) ? 512 : 256;
    const float* Ap = (k0 < 512) ? rseq : x;
    int astr = wstr;
    int kb = (k0 < 512) ? k0 : (k0 - 512);
    gemm_chunk_512(sW, sA, Wp, wstr, Ap, astr, m0, kb, t, ty, tx, acc);
  }
#pragma unroll
  for (int j = 0; j < 16; ++j) {
    int c = tx + 32 * j;
    float bb = Ub[c];
#pragma unroll
    for (int i = 0; i < 4; ++i) {
      float pre = acc[i][j] + bb;
      float g = 0.5f * pre * (1.f + erff(pre * 0.70710678118654752f));
      ht[(size_t)(m0 + ty * 4 + i) * 512 + c] = g;
    }
  }
}

// ---------------- K5: LN -> fftp GEMM -> final hs (in place) ----------------
__global__ __launch_bounds__(256) void k_final(
    const float* __restrict__ htg, const float* __restrict__ fftpw,
    const float* __restrict__ fftpb, const float* __restrict__ fg,
    const float* __restrict__ fmix, const float* __restrict__ cvec,
    const float* __restrict__ hm, float* __restrict__ hs)
{
  __shared__ float sHT[16][516];
  __shared__ float sW[512][20];
  const int t = threadIdx.x, ty = t >> 5, tx = t & 31;  // 8 groups x 2 rows, 16 cols
  const int m0 = blockIdx.x * 16;
  const int b = m0 >> 13;

#pragma unroll
  for (int i = 0; i < 8; ++i) {               // stage 16x512 h_tilde tile
    int idx = t + i * 256;                    // float4 index 0..2047
    int m = idx >> 7, c4 = idx & 127;
    float4 v = *reinterpret_cast<const float4*>(htg + (size_t)(m0 + m) * 512 + c4 * 4);
    *reinterpret_cast<float4*>(&sHT[m][c4 * 4]) = v;
  }
  __syncthreads();

  // per-row LN stats (rows ty*2 + i)
  float nm[2], rs[2];
#pragma unroll
  for (int i = 0; i < 2; ++i) {
    int r = ty * 2 + i;
    float s1 = 0.f, s2 = 0.f;
#pragma unroll
    for (int j = 0; j < 16; ++j) {
      float z = sHT[r][tx + 32 * j];
      s1 += z;
      s2 += z * z;
    }
#pragma unroll
    for (int m = 16; m >= 1; m >>= 1) {
      s1 += __shfl_xor(s1, m, 64);
      s2 += __shfl_xor(s2, m, 64);
    }
    float mean = s1 * (1.f / 512.f);
    float var = s2 * (1.f / 512.f) - mean * mean;
    float r_ = rsqrtf(var + 1e-5f);
    rs[i] = r_;
    nm[i] = -mean * r_;
  }

  float acc[2][16];
#pragma unroll
  for (int i = 0; i < 2; ++i)
#pragma unroll
    for (int j = 0; j < 16; ++j) acc[i][j] = 0.f;

  for (int k0 = 0; k0 < 512; k0 += 16) {
#pragma unroll
    for (int i = 0; i < 8; ++i) {             // stage fg-scaled fftp chunk
      int idx = t + i * 256;
      int n = idx >> 2, q4 = idx & 3;
      float4 v = *reinterpret_cast<const float4*>(fftpw + (size_t)n * 512 + k0 + q4 * 4);
      float4 gv = *reinterpret_cast<const float4*>(fg + k0 + q4 * 4);
      v.x *= gv.x; v.y *= gv.y; v.z *= gv.z; v.w *= gv.w;
      *reinterpret_cast<float4*>(&sW[n][q4 * 4]) = v;
    }
    __syncthreads();
#pragma unroll
    for (int kk = 0; kk < 16; kk += 4) {
      float4 a[2];
#pragma unroll
      for (int i = 0; i < 2; ++i) {
        float4 z = *reinterpret_cast<const float4*>(&sHT[ty * 2 + i][k0 + kk]);
        a[i].x = fmaf(z.x, rs[i], nm[i]);
        a[i].y = fmaf(z.y, rs[i], nm[i]);
        a[i].z = fmaf(z.z, rs[i], nm[i]);
        a[i].w = fmaf(z.w, rs[i], nm[i]);
      }
#pragma unroll
      for (int j = 0; j < 16; ++j) {
        float4 w = *reinterpret_cast<const float4*>(&sW[tx + 32 * j][kk]);
#pragma unroll
        for (int i = 0; i < 2; ++i) {
          acc[i][j] = fmaf(a[i].x, w.x, acc[i][j]);
          acc[i][j] = fmaf(a[i].y, w.y, acc[i][j]);
          acc[i][j] = fmaf(a[i].z, w.z, acc[i][j]);
          acc[i][j] = fmaf(a[i].w, w.w, acc[i][j]);
        }
      }
    }
    __syncthreads();
  }

  const float s = 1.f / (1.f + expf(-fmix[0]));
  const float s2 = s * s;
#pragma unroll
  for (int j = 0; j < 16; ++j) {
    int c = tx + 32 * j;
    float fpb = fftpb[c], cv = cvec[c], hmv = hm[b * 512 + c];
#pragma unroll
    for (int i = 0; i < 2; ++i) {
      int r = ty * 2 + i;
      float htv = sHT[r][c];
      float out = (1.f - s) * htv + s2 * (acc[i][j] + cv) + s * fpb + 0.5f * hmv;
      hs[(size_t)(m0 + r) * 512 + c] = out;
    }
  }
}

extern "C" void kernel_launch(void* const* d_in, const int* in_sizes, int n_in,
                              void* d_out, int out_size, void* d_ws, size_t ws_size,
                              hipStream_t stream)
{
  (void)in_sizes; (void)n_in; (void)out_size; (void)ws_size;
  const float* x     = (const float*)d_in[0];
  const float* Wxw   = (const float*)d_in[1];
  const float* Wxb   = (const float*)d_in[2];
  const float* resa  = (const float*)d_in[4];
  const float* Bw    = (const float*)d_in[6];
  const float* Uw    = (const float*)d_in[7];
  const float* Ub    = (const float*)d_in[8];
  const float* fg    = (const float*)d_in[9];   // fftn_g
  const float* fb    = (const float*)d_in[10];  // fftn_b
  const float* fftpw = (const float*)d_in[11];
  const float* fftpb = (const float*)d_in[12];
  const float* fmix  = (const float*)d_in[13];
  const float* mixl  = (const float*)d_in[14];
  const float* keyw  = (const float*)d_in[15];
  const float* keyb  = (const float*)d_in[16];
  const float* rmw   = (const float*)d_in[19];
  const float* rmb   = (const float*)d_in[20];
  const float* rng   = (const float*)d_in[21];
  const float* rnb   = (const float*)d_in[22];
  const float* mkeys = (const float*)d_in[23];
  const float* mvals = (const float*)d_in[24];
  const float* hebH  = (const float*)d_in[25];

  float* outp = (float*)d_out;
  float* hs   = outp;                               // (B,T,512)
  float* rout = outp + (size_t)65536 * 512;         // (B,T,512)
  float* ws   = (float*)d_ws;
  float* q_ws = ws;                                 // 1024 floats
  float* hm   = ws + 1024;                          // 4096 floats
  float* cvec = ws + 1024 + 4096;                   // 512 floats
  float* partial = hs;                              // hs region is scratch until K4

  k_rseq  <<<2048, 256, 0, stream>>>(x, Wxw, Wxb, resa, rng, rnb, rout);
  k_kq    <<<2048, 256, 0, stream>>>(rout, x, keyw, keyb, partial);
  k_qred  <<<4,    256, 0, stream>>>(partial, q_ws);
  k_cvec  <<<2,    256, 0, stream>>>(fb, fftpw, cvec);
  k_mem   <<<8,    256, 0, stream>>>(q_ws, mkeys, mvals, hebH, rmw, rmb, mixl, hm);
  k_htilde<<<2048, 256, 0, stream>>>(rout, x, Bw, Uw, Ub, hs);
  k_final <<<4096, 256, 0, stream>>>(hs, fftpw, fftpb, fg, fmix, cvec, hm, hs);
}

// Round 2
// 629.226 us; speedup vs baseline: 7.0643x; 7.0643x over previous
//
#include <hip/hip_runtime.h>
#include <cmath>

// CRSDCell bf16-MFMA pipeline (mfma_f32_32x32x16_bf16):
//  k_wconv : weights fp32 -> bf16 in ws (fftp scaled by fftn_g)
//  k_rseq  : r = LN((1-a)*tanh(x@Wx^T+b)) -> d_out r region   [MFMA, BM=128]
//  k_kq    : k=[r,x]@key^T+b; colsum of l2norm(k) partials    [MFMA, BM=128]
//  k_qred  : q = mean over T
//  k_cvec  : cvec = fftn_b @ fftp_w^T
//  k_mem   : top-k episodic + hebbian + rm -> h_mem
//  k_fused : h~=gelu(r@B^T+x@U^T+Ub); LN; GEMM2 @ (fftp*g)^T; combine -> hs
//            [MFMA, BM=64, h_norm kept in swizzled LDS, h~ kept packed in regs]
// FFT folds exactly: irfft(rfft(h)*s) = s*h. h_prev=r_prev=0 kills Wh/A terms.

typedef __attribute__((ext_vector_type(8)))  short short8;
typedef __attribute__((ext_vector_type(16))) float f32x16;

__device__ __forceinline__ unsigned short f2bf(float f) {
  union { float f; unsigned u; } v; v.f = f;
  unsigned r = v.u + 0x7FFF + ((v.u >> 16) & 1);   // RTNE
  return (unsigned short)(r >> 16);
}
__device__ __forceinline__ float bf2f(unsigned short h) {
  union { unsigned u; float f; } v; v.u = ((unsigned)h) << 16; return v.f;
}
__device__ __forceinline__ f32x16 mfma16(short8 a, short8 b, f32x16 c) {
  return __builtin_amdgcn_mfma_f32_32x32x16_bf16(a, b, c, 0, 0, 0);
}

// stage ROWS x 32 fp32 chunk -> bf16 LDS tile [ROWS][32]
template <int NT>
__device__ __forceinline__ void stage_act(short* dst, const float* __restrict__ src,
                                          int stride, int rows, int t) {
  int total = rows * 8;                      // float4 chunks
  for (int c = t; c < total; c += NT) {
    int row = c >> 3, kq = c & 7;
    float4 v = *reinterpret_cast<const float4*>(src + (size_t)row * stride + kq * 4);
    unsigned lo = (unsigned)f2bf(v.x) | ((unsigned)f2bf(v.y) << 16);
    unsigned hi = (unsigned)f2bf(v.z) | ((unsigned)f2bf(v.w) << 16);
    uint2 p; p.x = lo; p.y = hi;
    *reinterpret_cast<uint2*>(dst + row * 32 + kq * 4) = p;
  }
}

// stage ROWS x 32 bf16 weight chunk (row-major [n][K]) -> LDS [ROWS][32]
template <int NT>
__device__ __forceinline__ void stage_w(short* dst, const unsigned short* __restrict__ w,
                                        int K, int rows, int t) {
  int total = rows * 4;                      // 16B chunks
  for (int c = t; c < total; c += NT) {
    int row = c >> 2, p = c & 3;
    short8 v = *reinterpret_cast<const short8*>(w + (size_t)row * K + p * 8);
    *reinterpret_cast<short8*>(dst + row * 32 + p * 8) = v;
  }
}

// ---------------- weight convert ----------------
__global__ __launch_bounds__(256) void k_wconv(
    const float* __restrict__ wx, const float* __restrict__ key,
    const float* __restrict__ bw, const float* __restrict__ uw,
    const float* __restrict__ fftpw, const float* __restrict__ fg,
    unsigned short* __restrict__ o) {
  int i = blockIdx.x * 256 + threadIdx.x;
  if (i >= 884736) return;
  float v;
  if (i < 131072)      v = wx[i];
  else if (i < 229376) v = key[i - 131072];
  else if (i < 491520) v = bw[i - 229376];
  else if (i < 622592) v = uw[i - 491520];
  else { int j = i - 622592; v = fftpw[j] * fg[j & 511]; }
  o[i] = f2bf(v);
}

// ---------------- K1: r_seq (MFMA) ----------------
// 512 thr = 8 waves (2m x 4n), BM=128, N=512, K=256
__global__ __launch_bounds__(512, 2) void k_rseq(
    const float* __restrict__ x, const unsigned short* __restrict__ wx,
    const float* __restrict__ wxb, const float* __restrict__ resa,
    const float* __restrict__ rng, const float* __restrict__ rnb,
    float* __restrict__ rout) {
  __shared__ short sA[128 * 32];
  __shared__ short sW[512 * 32];
  const int t = threadIdx.x, w = t >> 6, lane = t & 63, lr = lane & 31, lh = lane >> 5;
  const int mw = w >> 2, nw = w & 3;
  const int m0 = blockIdx.x * 128;

  f32x16 acc[2][4];
#pragma unroll
  for (int mi = 0; mi < 2; ++mi)
#pragma unroll
    for (int ni = 0; ni < 4; ++ni)
#pragma unroll
      for (int e = 0; e < 16; ++e) acc[mi][ni][e] = 0.f;

  for (int k0 = 0; k0 < 256; k0 += 32) {
    stage_act<512>(sA, x + (size_t)m0 * 256 + k0, 256, 128, t);
    stage_w<512>(sW, wx + k0, 256, 512, t);
    __syncthreads();
#pragma unroll
    for (int kh = 0; kh < 2; ++kh) {
      short8 a[2], b[4];
#pragma unroll
      for (int mi = 0; mi < 2; ++mi)
        a[mi] = *reinterpret_cast<const short8*>(&sA[(64 * mw + 32 * mi + lr) * 32 + kh * 16 + 8 * lh]);
#pragma unroll
      for (int ni = 0; ni < 4; ++ni)
        b[ni] = *reinterpret_cast<const short8*>(&sW[(128 * nw + 32 * ni + lr) * 32 + kh * 16 + 8 * lh]);
#pragma unroll
      for (int mi = 0; mi < 2; ++mi)
#pragma unroll
        for (int ni = 0; ni < 4; ++ni)
          acc[mi][ni] = mfma16(a[mi], b[ni], acc[mi][ni]);
    }
    __syncthreads();
  }

  // z = (1-alpha)*tanh(acc + b)
#pragma unroll
  for (int ni = 0; ni < 4; ++ni) {
    int col = 128 * nw + 32 * ni + lr;
    float al = 1.f / (1.f + expf(-resa[col >> 7]));
    float oma = 1.f - al, bb = wxb[col];
#pragma unroll
    for (int mi = 0; mi < 2; ++mi)
#pragma unroll
      for (int r = 0; r < 16; ++r)
        acc[mi][ni][r] = oma * tanhf(acc[mi][ni][r] + bb);
  }
  // LN stats: red1[4nw][4 mrow][32] @0, red2 @512, stats(float2) @1024
  float* red = reinterpret_cast<float*>(sW);
#pragma unroll
  for (int mi = 0; mi < 2; ++mi) {
    int mrow = mw * 2 + mi;
#pragma unroll
    for (int r = 0; r < 16; ++r) {
      float s1 = acc[mi][0][r] + acc[mi][1][r] + acc[mi][2][r] + acc[mi][3][r];
      float s2 = acc[mi][0][r] * acc[mi][0][r] + acc[mi][1][r] * acc[mi][1][r] +
                 acc[mi][2][r] * acc[mi][2][r] + acc[mi][3][r] * acc[mi][3][r];
#pragma unroll
      for (int m = 1; m <= 16; m <<= 1) { s1 += __shfl_xor(s1, m); s2 += __shfl_xor(s2, m); }
      int rl = (r & 3) + 8 * (r >> 2) + 4 * lh;
      if (lr == r) { red[(nw * 4 + mrow) * 32 + rl] = s1; red[512 + (nw * 4 + mrow) * 32 + rl] = s2; }
    }
  }
  __syncthreads();
  if (t < 128) {
    int mrow = t >> 5, rl = t & 31;
    float s1 = 0.f, s2 = 0.f;
#pragma unroll
    for (int n = 0; n < 4; ++n) { s1 += red[(n * 4 + mrow) * 32 + rl]; s2 += red[512 + (n * 4 + mrow) * 32 + rl]; }
    float mean = s1 * (1.f / 512.f);
    float var = s2 * (1.f / 512.f) - mean * mean;
    float rstd = rsqrtf(var + 1e-5f);
    red[1024 + (mrow * 32 + rl) * 2] = mean;
    red[1024 + (mrow * 32 + rl) * 2 + 1] = rstd;
  }
  __syncthreads();
#pragma unroll
  for (int mi = 0; mi < 2; ++mi) {
    int mrow = mw * 2 + mi;
#pragma unroll
    for (int q = 0; q < 4; ++q) {
      float4 stA = *reinterpret_cast<float4*>(&red[1024 + (mrow * 32 + 8 * q + 4 * lh) * 2]);
      float4 stB = *reinterpret_cast<float4*>(&red[1024 + (mrow * 32 + 8 * q + 4 * lh) * 2 + 4]);
      float mean[4] = {stA.x, stA.z, stB.x, stB.z};
      float rstd[4] = {stA.y, stA.w, stB.y, stB.w};
#pragma unroll
      for (int ni = 0; ni < 4; ++ni) {
        int col = 128 * nw + 32 * ni + lr;
        float g = rng[col], bb = rnb[col];
#pragma unroll
        for (int e = 0; e < 4; ++e) {
          int r = 4 * q + e;
          int grow = m0 + 64 * mw + 32 * mi + 8 * q + 4 * lh + e;
          rout[(size_t)grow * 512 + col] = (acc[mi][ni][r] - mean[e]) * rstd[e] * g + bb;
        }
      }
    }
  }
}

// ---------------- K2: k + q partials (MFMA) ----------------
// 256 thr = 4 waves (2m x 2n), BM=128, N=128, K=768
__global__ __launch_bounds__(256) void k_kq(
    const float* __restrict__ rseq, const float* __restrict__ x,
    const unsigned short* __restrict__ key, const float* __restrict__ keyb,
    float* __restrict__ partial) {
  __shared__ short sA[128 * 32];
  __shared__ short sW[128 * 32];
  const int t = threadIdx.x, w = t >> 6, lane = t & 63, lr = lane & 31, lh = lane >> 5;
  const int mw = w >> 1, nw = w & 1;
  const int m0 = blockIdx.x * 128;

  f32x16 acc[2][2];
#pragma unroll
  for (int mi = 0; mi < 2; ++mi)
#pragma unroll
    for (int ni = 0; ni < 2; ++ni)
#pragma unroll
      for (int e = 0; e < 16; ++e) acc[mi][ni][e] = 0.f;

  for (int k0 = 0; k0 < 768; k0 += 32) {
    if (k0 < 512) stage_act<256>(sA, rseq + (size_t)m0 * 512 + k0, 512, 128, t);
    else          stage_act<256>(sA, x + (size_t)m0 * 256 + (k0 - 512), 256, 128, t);
    stage_w<256>(sW, key + k0, 768, 128, t);
    __syncthreads();
#pragma unroll
    for (int kh = 0; kh < 2; ++kh) {
      short8 a[2], b[2];
#pragma unroll
      for (int mi = 0; mi < 2; ++mi)
        a[mi] = *reinterpret_cast<const short8*>(&sA[(64 * mw + 32 * mi + lr) * 32 + kh * 16 + 8 * lh]);
#pragma unroll
      for (int ni = 0; ni < 2; ++ni)
        b[ni] = *reinterpret_cast<const short8*>(&sW[(64 * nw + 32 * ni + lr) * 32 + kh * 16 + 8 * lh]);
#pragma unroll
      for (int mi = 0; mi < 2; ++mi)
#pragma unroll
        for (int ni = 0; ni < 2; ++ni)
          acc[mi][ni] = mfma16(a[mi], b[ni], acc[mi][ni]);
    }
    __syncthreads();
  }

  // + bias
#pragma unroll
  for (int ni = 0; ni < 2; ++ni) {
    int col = 64 * nw + 32 * ni + lr;
    float bb = keyb[col];
#pragma unroll
    for (int mi = 0; mi < 2; ++mi)
#pragma unroll
      for (int r = 0; r < 16; ++r) acc[mi][ni][r] += bb;
  }
  // per-row sumsq -> red[2nw][4 mrow][32] @0; scale @256; qp @384
  float* red = reinterpret_cast<float*>(sA);
#pragma unroll
  for (int mi = 0; mi < 2; ++mi) {
    int mrow = mw * 2 + mi;
#pragma unroll
    for (int r = 0; r < 16; ++r) {
      float s2 = acc[mi][0][r] * acc[mi][0][r] + acc[mi][1][r] * acc[mi][1][r];
#pragma unroll
      for (int m = 1; m <= 16; m <<= 1) s2 += __shfl_xor(s2, m);
      int rl = (r & 3) + 8 * (r >> 2) + 4 * lh;
      if (lr == r) red[(nw * 4 + mrow) * 32 + rl] = s2;
    }
  }
  __syncthreads();
  if (t < 128) {
    int mrow = t >> 5, rl = t & 31;
    float s = red[(0 * 4 + mrow) * 32 + rl] + red[(1 * 4 + mrow) * 32 + rl];
    red[256 + mrow * 32 + rl] = 1.f / fmaxf(sqrtf(s), 1e-8f);
  }
  __syncthreads();
  float p0 = 0.f, p1 = 0.f;
#pragma unroll
  for (int mi = 0; mi < 2; ++mi) {
    int mrow = mw * 2 + mi;
#pragma unroll
    for (int q = 0; q < 4; ++q) {
      float4 sc4 = *reinterpret_cast<float4*>(&red[256 + mrow * 32 + 8 * q + 4 * lh]);
      float sc[4] = {sc4.x, sc4.y, sc4.z, sc4.w};
#pragma unroll
      for (int e = 0; e < 4; ++e) {
        int r = 4 * q + e;
        p0 += acc[mi][0][r] * sc[e];
        p1 += acc[mi][1][r] * sc[e];
      }
    }
  }
  p0 += __shfl_xor(p0, 32);
  p1 += __shfl_xor(p1, 32);
  if (lh == 0) {
    red[384 + mw * 128 + 64 * nw + lr]      = p0;
    red[384 + mw * 128 + 64 * nw + 32 + lr] = p1;
  }
  __syncthreads();
  if (t < 128) partial[(size_t)blockIdx.x * 128 + t] = red[384 + t] + red[384 + 128 + t];
}

// ---------------- q reduce ----------------
__global__ __launch_bounds__(256) void k_qred(const float* __restrict__ partial,
                                              float* __restrict__ q_ws) {
  int gid = blockIdx.x * 256 + threadIdx.x;   // 0..1023
  int b = gid >> 7, c = gid & 127;
  float s = 0.f;
  for (int i = 0; i < 64; ++i) s += partial[(size_t)(b * 64 + i) * 128 + c];
  q_ws[gid] = s * (1.f / 8192.f);
}

// ---------------- cvec = fftn_b @ fftp_w^T ----------------
__global__ __launch_bounds__(256) void k_cvec(const float* __restrict__ fb,
                                              const float* __restrict__ fftpw,
                                              float* __restrict__ cvec) {
  int o = blockIdx.x * 256 + threadIdx.x;     // 0..511
  const float* w = fftpw + (size_t)o * 512;
  float s = 0.f;
  for (int k = 0; k < 512; ++k) s += fb[k] * w[k];
  cvec[o] = s;
}

// ---------------- memory (episodic + hebbian) ----------------
__global__ __launch_bounds__(256) void k_mem(
    const float* __restrict__ q_ws, const float* __restrict__ mkeys,
    const float* __restrict__ mvals, const float* __restrict__ hebH,
    const float* __restrict__ rmw, const float* __restrict__ rmb,
    const float* __restrict__ mixl, float* __restrict__ hm) {
  const int b = blockIdx.x, t = threadIdx.x;
  __shared__ float qv[128];
  __shared__ float ssim[256];
  __shared__ float red[256];
  __shared__ float tval[8];
  __shared__ int tidx[8];
  __shared__ float wsm[8];
  __shared__ float vcs[128];

  if (t < 128) qv[t] = q_ws[b * 128 + t];
  __syncthreads();
  red[t] = (t < 128) ? qv[t] * qv[t] : 0.f;
  __syncthreads();
  for (int s = 128; s > 0; s >>= 1) {
    if (t < s) red[t] += red[t + s];
    __syncthreads();
  }
  float qsc = 1.f / fmaxf(sqrtf(red[0]), 1e-8f);
  {
    const float* mk = mkeys + ((size_t)b * 256 + t) * 128;
    float dot = 0.f, ms = 0.f;
    for (int k = 0; k < 128; ++k) { float mv = mk[k]; dot += qv[k] * mv; ms += mv * mv; }
    ssim[t] = dot * qsc / fmaxf(sqrtf(ms), 1e-8f);
  }
  __syncthreads();
  for (int it = 0; it < 8; ++it) {
    if (t < 64) {
      float bv = -1e30f; int bi = 0;
#pragma unroll
      for (int u = 0; u < 4; ++u) {
        int m = t * 4 + u;
        float v = ssim[m];
        if (v > bv) { bv = v; bi = m; }
      }
      for (int off = 32; off; off >>= 1) {
        float ov = __shfl_xor(bv, off, 64);
        int oi = __shfl_xor(bi, off, 64);
        if (ov > bv || (ov == bv && oi < bi)) { bv = ov; bi = oi; }
      }
      if (t == 0) { tval[it] = bv; tidx[it] = bi; ssim[bi] = -1e30f; }
    }
    __syncthreads();
  }
  if (t == 0) {
    float m0 = tval[0], sum = 0.f, e[8];
#pragma unroll
    for (int i = 0; i < 8; ++i) { e[i] = expf(tval[i] - m0); sum += e[i]; }
#pragma unroll
    for (int i = 0; i < 8; ++i) wsm[i] = e[i] / sum;
  }
  __syncthreads();
  float mix = 1.f / (1.f + expf(-mixl[0]));
  if (t < 128) {
    float vh = 0.f;
#pragma unroll
    for (int i = 0; i < 8; ++i) vh += wsm[i] * mvals[((size_t)b * 256 + tidx[i]) * 128 + t];
    float vhb = 0.f;
    const float* H = hebH + (size_t)b * 128 * 128;
    for (int k = 0; k < 128; ++k) vhb += qv[k] * H[k * 128 + t];
    vcs[t] = mix * vh + (1.f - mix) * vhb;
  }
  __syncthreads();
  for (int h = t; h < 512; h += 256) {
    float sum = rmb[h];
    const float* wr = rmw + (size_t)h * 128;
    for (int v = 0; v < 128; ++v) sum += vcs[v] * wr[v];
    hm[b * 512 + h] = sum;
  }
}

// ---------------- fused h_tilde -> LN -> fftp GEMM -> hs ----------------
// 512 thr = 8 waves (2m x 4n), BM=64, GEMM1 K=768, GEMM2 K=512
__global__ __launch_bounds__(512, 2) void k_fused(
    const float* __restrict__ rseq, const float* __restrict__ x,
    const unsigned short* __restrict__ bw, const unsigned short* __restrict__ uw,
    const float* __restrict__ ub, const unsigned short* __restrict__ fftps,
    const float* __restrict__ fftpb, const float* __restrict__ fmix,
    const float* __restrict__ cvec, const float* __restrict__ hm,
    float* __restrict__ hs) {
  __shared__ short sH[64 * 512];   // h_norm bf16, XOR-swizzled; first 4KB doubles as A-tile
  __shared__ short sW[512 * 32];
  const int t = threadIdx.x, w = t >> 6, lane = t & 63, lr = lane & 31, lh = lane >> 5;
  const int mw = w >> 2, nw = w & 3;
  const int m0 = blockIdx.x * 64;
  const int bidx = m0 >> 13;
  short* sA = sH;

  f32x16 acc[4];
#pragma unroll
  for (int ni = 0; ni < 4; ++ni)
#pragma unroll
    for (int e = 0; e < 16; ++e) acc[ni][e] = 0.f;

  // ---- GEMM1: h_pre = [r,x] @ [Bw,Uw]^T ----
  for (int k0 = 0; k0 < 768; k0 += 32) {
    if (k0 < 512) stage_act<512>(sA, rseq + (size_t)m0 * 512 + k0, 512, 64, t);
    else          stage_act<512>(sA, x + (size_t)m0 * 256 + (k0 - 512), 256, 64, t);
    if (k0 < 512) stage_w<512>(sW, bw + k0, 512, 512, t);
    else          stage_w<512>(sW, uw + (k0 - 512), 256, 512, t);
    __syncthreads();
#pragma unroll
    for (int kh = 0; kh < 2; ++kh) {
      short8 a = *reinterpret_cast<const short8*>(&sA[(32 * mw + lr) * 32 + kh * 16 + 8 * lh]);
      short8 b[4];
#pragma unroll
      for (int ni = 0; ni < 4; ++ni)
        b[ni] = *reinterpret_cast<const short8*>(&sW[(128 * nw + 32 * ni + lr) * 32 + kh * 16 + 8 * lh]);
#pragma unroll
      for (int ni = 0; ni < 4; ++ni)
        acc[ni] = mfma16(a, b[ni], acc[ni]);
    }
    __syncthreads();
  }

  // ---- epilogue1: gelu, LN stats, write swizzled h_norm, pack h_tilde ----
#pragma unroll
  for (int ni = 0; ni < 4; ++ni) {
    int col = 128 * nw + 32 * ni + lr;
    float ubc = ub[col];
#pragma unroll
    for (int r = 0; r < 16; ++r) {
      float pre = acc[ni][r] + ubc;
      acc[ni][r] = 0.5f * pre * (1.f + erff(pre * 0.70710678118654752f));
    }
  }
  float* red = reinterpret_cast<float*>(sW);  // red1[4nw][2mw][32]@0, red2@256, stats(f2)@512
#pragma unroll
  for (int r = 0; r < 16; ++r) {
    float s1 = acc[0][r] + acc[1][r] + acc[2][r] + acc[3][r];
    float s2 = acc[0][r] * acc[0][r] + acc[1][r] * acc[1][r] +
               acc[2][r] * acc[2][r] + acc[3][r] * acc[3][r];
#pragma unroll
    for (int m = 1; m <= 16; m <<= 1) { s1 += __shfl_xor(s1, m); s2 += __shfl_xor(s2, m); }
    int rl = (r & 3) + 8 * (r >> 2) + 4 * lh;
    if (lr == r) { red[(nw * 2 + mw) * 32 + rl] = s1; red[256 + (nw * 2 + mw) * 32 + rl] = s2; }
  }
  __syncthreads();
  if (w == 0) {
    int mw_ = lane >> 5, rl = lane & 31;
    float s1 = 0.f, s2 = 0.f;
#pragma unroll
    for (int n = 0; n < 4; ++n) { s1 += red[(n * 2 + mw_) * 32 + rl]; s2 += red[256 + (n * 2 + mw_) * 32 + rl]; }
    float mean = s1 * (1.f / 512.f);
    float var = s2 * (1.f / 512.f) - mean * mean;
    float rstd = rsqrtf(var + 1e-5f);
    red[512 + (mw_ * 32 + rl) * 2] = mean;
    red[512 + (mw_ * 32 + rl) * 2 + 1] = rstd;
  }
  __syncthreads();
  unsigned htp[4][8];
#pragma unroll
  for (int ni = 0; ni < 4; ++ni)
#pragma unroll
    for (int p = 0; p < 8; ++p)
      htp[ni][p] = (unsigned)f2bf(acc[ni][2 * p]) | ((unsigned)f2bf(acc[ni][2 * p + 1]) << 16);
#pragma unroll
  for (int q = 0; q < 4; ++q) {
    float4 stA = *reinterpret_cast<float4*>(&red[512 + (mw * 32 + 8 * q + 4 * lh) * 2]);
    float4 stB = *reinterpret_cast<float4*>(&red[512 + (mw * 32 + 8 * q + 4 * lh) * 2 + 4]);
    float mean[4] = {stA.x, stA.z, stB.x, stB.z};
    float rstd[4] = {stA.y, stA.w, stB.y, stB.w};
#pragma unroll
    for (int ni = 0; ni < 4; ++ni) {
      int col = 128 * nw + 32 * ni + lr;
#pragma unroll
      for (int e = 0; e < 4; ++e) {
        int r = 4 * q + e;
        float z = (acc[ni][r] - mean[e]) * rstd[e];
        int rloc = 32 * mw + 8 * q + 4 * lh + e;
        int idx = rloc * 512 + (((col >> 3) ^ (rloc & 7)) << 3) + (col & 7);
        sH[idx] = (short)f2bf(z);
      }
    }
  }
#pragma unroll
  for (int ni = 0; ni < 4; ++ni)
#pragma unroll
    for (int e = 0; e < 16; ++e) acc[ni][e] = 0.f;
  __syncthreads();

  // ---- GEMM2: h_norm @ (fftp*g)^T ----
  for (int k0 = 0; k0 < 512; k0 += 32) {
    stage_w<512>(sW, fftps + k0, 512, 512, t);
    __syncthreads();
#pragma unroll
    for (int kh = 0; kh < 2; ++kh) {
      int row = 32 * mw + lr;
      int k8 = k0 + kh * 16 + 8 * lh;
      short8 a = *reinterpret_cast<const short8*>(&sH[row * 512 + (((k8 >> 3) ^ (row & 7)) << 3)]);
      short8 b[4];
#pragma unroll
      for (int ni = 0; ni < 4; ++ni)
        b[ni] = *reinterpret_cast<const short8*>(&sW[(128 * nw + 32 * ni + lr) * 32 + kh * 16 + 8 * lh]);
#pragma unroll
      for (int ni = 0; ni < 4; ++ni)
        acc[ni] = mfma16(a, b[ni], acc[ni]);
    }
    __syncthreads();
  }

  // ---- epilogue2: combine ----
  const float s = 1.f / (1.f + expf(-fmix[0]));
  const float s2f = s * s, oms = 1.f - s;
#pragma unroll
  for (int ni = 0; ni < 4; ++ni) {
    int col = 128 * nw + 32 * ni + lr;
    float base = s2f * cvec[col] + s * fftpb[col] + 0.5f * hm[bidx * 512 + col];
#pragma unroll
    for (int p = 0; p < 8; ++p) {
      unsigned pk = htp[ni][p];
      int r0 = 2 * p;
      int rloc = 32 * mw + (r0 & 3) + 8 * (r0 >> 2) + 4 * lh;
      float o0 = oms * bf2f((unsigned short)(pk & 0xFFFF)) + s2f * acc[ni][r0] + base;
      float o1 = oms * bf2f((unsigned short)(pk >> 16)) + s2f * acc[ni][r0 + 1] + base;
      hs[(size_t)(m0 + rloc) * 512 + col] = o0;
      hs[(size_t)(m0 + rloc + 1) * 512 + col] = o1;
    }
  }
}

extern "C" void kernel_launch(void* const* d_in, const int* in_sizes, int n_in,
                              void* d_out, int out_size, void* d_ws, size_t ws_size,
                              hipStream_t stream) {
  (void)in_sizes; (void)n_in; (void)out_size; (void)ws_size;
  const float* x     = (const float*)d_in[0];
  const float* Wxw   = (const float*)d_in[1];
  const float* Wxb   = (const float*)d_in[2];
  const float* resa  = (const float*)d_in[4];
  const float* Bw    = (const float*)d_in[6];
  const float* Uw    = (const float*)d_in[7];
  const float* Ub    = (const float*)d_in[8];
  const float* fg    = (const float*)d_in[9];
  const float* fb    = (const float*)d_in[10];
  const float* fftpw = (const float*)d_in[11];
  const float* fftpb = (const float*)d_in[12];
  const float* fmix  = (const float*)d_in[13];
  const float* mixl  = (const float*)d_in[14];
  const float* keyw  = (const float*)d_in[15];
  const float* keyb  = (const float*)d_in[16];
  const float* rmw   = (const float*)d_in[19];
  const float* rmb   = (const float*)d_in[20];
  const float* rng   = (const float*)d_in[21];
  const float* rnb   = (const float*)d_in[22];
  const float* mkeys = (const float*)d_in[23];
  const float* mvals = (const float*)d_in[24];
  const float* hebH  = (const float*)d_in[25];

  float* outp = (float*)d_out;
  float* hs   = outp;                               // (B,T,512)
  float* rout = outp + (size_t)65536 * 512;         // (B,T,512)

  unsigned short* wsu = (unsigned short*)d_ws;
  const unsigned short* wxb16  = wsu;               // 512x256  @0
  const unsigned short* keyb16 = wsu + 131072;      // 128x768
  const unsigned short* bwb16  = wsu + 229376;      // 512x512
  const unsigned short* uwb16  = wsu + 491520;      // 512x256
  const unsigned short* fftpb16= wsu + 622592;      // 512x512 (g-scaled)
  float* wsf     = (float*)d_ws;
  float* partial = wsf + 524288;                    // 512*128
  float* q_ws    = wsf + 589824;                    // 1024
  float* hm      = wsf + 590848;                    // 4096
  float* cvec    = wsf + 594944;                    // 512

  k_wconv<<<3456, 256, 0, stream>>>(Wxw, keyw, Bw, Uw, fftpw, fg, wsu);
  k_cvec <<<2,    256, 0, stream>>>(fb, fftpw, cvec);
  k_rseq <<<512,  512, 0, stream>>>(x, wxb16, Wxb, resa, rng, rnb, rout);
  k_kq   <<<512,  256, 0, stream>>>(rout, x, keyb16, keyb, partial);
  k_qred <<<4,    256, 0, stream>>>(partial, q_ws);
  k_mem  <<<8,    256, 0, stream>>>(q_ws, mkeys, mvals, hebH, rmw, rmb, mixl, hm);
  k_fused<<<1024, 512, 0, stream>>>(rout, x, bwb16, uwb16, Ub, fftpb16, fftpb,
                                    fmix, cvec, hm, hs);
}